// Round 4
// baseline (365.133 us; speedup 1.0000x reference)
//
#include <hip/hip_runtime.h>
#include <stdint.h>

#define L1D 3072
#define NB 16384
#define CAP 4096            // per-bucket capacity in sorted[]: 2048 mean +48 sigma

typedef float  float4v  __attribute__((ext_vector_type(4)));
typedef short  short8   __attribute__((ext_vector_type(8)));

__device__ __forceinline__ unsigned short f2bf(float f) {
  uint32_t u = __builtin_bit_cast(uint32_t, f);
  u += 0x7fffu + ((u >> 16) & 1u);   // RNE; inputs are finite
  return (unsigned short)(u >> 16);
}

__device__ __forceinline__ void gload_lds16(const void* g, void* l) {
  __builtin_amdgcn_global_load_lds((const __attribute__((address_space(1))) unsigned int*)g,
                                   (__attribute__((address_space(3))) unsigned int*)l, 16, 0, 0);
}

// Combined weights PRE-FRAGMENTED in MFMA B-fragment order:
//   frag(ntile, kk, lane) = 16B at ((ntile*96 + kk)*64 + lane)*8 shorts
//   lane l = sub*16 + r holds W[ntile*16 + r][kk*32 + sub*8 .. +8]
// Also zeroes the bucket cursors (workspace is re-poisoned every iteration).
__global__ void prep_kernel(const float* __restrict__ l1w, const float* __restrict__ l1b,
                            const float* __restrict__ l1fw, const float* __restrict__ l1fb,
                            unsigned short* __restrict__ cw, float* __restrict__ cb,
                            int* __restrict__ cur) {
  const int n = blockIdx.y;                       // 0..127  (= bucket*16 + j)
  const int k = blockIdx.x * 256 + threadIdx.x;   // 0..3071
  const unsigned short v = f2bf(l1w[n * L1D + k] + l1fw[(n & 15) * L1D + k]);
  const int kk  = k >> 5;
  const int sub = (k >> 3) & 3;
  const int e   = k & 7;
  const int lane = sub * 16 + (n & 15);
  cw[(((n >> 4) * 96 + kk) * 64 + lane) * 8 + e] = v;
  if (blockIdx.x == 0 && n == 0 && threadIdx.x < 128)
    cb[threadIdx.x] = l1b[threadIdx.x] + l1fb[threadIdx.x & 15];
  if (blockIdx.x == 0 && n == 0 && threadIdx.x < 8) cur[threadIdx.x] = 0;
}

// Bucket-sort row indices (order within bucket irrelevant).
__global__ void scatter_kernel(const int* __restrict__ lsi, int* __restrict__ cur,
                               int* __restrict__ sorted) {
  const int i = blockIdx.x * 256 + threadIdx.x;
  const int b = lsi[i];
  const int pos = atomicAdd(&cur[b], 1);
  sorted[b * CAP + pos] = i;
}

struct __align__(16) EpS {
  float ygp[2][32][20];               // k-parity partial sums, padded stride
  float l2wb[960];                    // bucket slice of l2_w  [n*30+k]
  float outwb[32];
  float l2bb[32];
  float biasb[16];
  int   rows[32];
};                                    // 9408 B

union __align__(16) SMem {
  struct { char slab[4][2][6144]; } st;   // [wave][buf][ A:0..4095 | B:4096..6143 ]  = 48 KiB
  EpS ep;
};

// Per-block: 32 rows of ONE bucket -> one 16-col B tile. Waves split
// (m-half h, K-parity p); each streams its own 24 K-tiles through a
// wave-PRIVATE LDS double buffer with per-wave counted vmcnt -- no barriers
// in the main loop. 3 blocks/CU (48 KiB LDS); ~8-12 independent waves/CU
// keep 50-100 KB of HBM loads in flight.
__global__ __launch_bounds__(256, 3) void fused_kernel(
    const float* __restrict__ x, const unsigned short* __restrict__ cw,
    const float* __restrict__ cb,
    const float* __restrict__ gl2w, const float* __restrict__ gl2b,
    const float* __restrict__ goutw, const float* __restrict__ goutb,
    const int* __restrict__ cur, const int* __restrict__ sorted,
    float* __restrict__ out) {
  __shared__ SMem sm;
  const int tid  = threadIdx.x;
  const int lane = tid & 63;
  const int wid  = tid >> 6;
  const int bucket = blockIdx.x >> 7;
  const int chunk  = blockIdx.x & 127;
  const int count  = cur[bucket];
  const int start  = chunk * 32;
  if (start >= count) return;          // uniform: whole block exits before any barrier

  const int h = wid >> 1;              // m-half: rows h*16 .. h*16+15
  const int p = wid & 1;               // K-parity: tiles {p, p+2, ..., 46+p}

  // Per-lane global A pointers for the 4 stage-instructions (4 rows each).
  // XOR swizzle applied on the SOURCE column chunk (linear LDS dest; read
  // applies the same XOR) -> conflict-free frag reads.
  const char* aP[4];
#pragma unroll
  for (int q = 0; q < 4; ++q) {
    const int lr = q * 4 + (lane >> 4);                  // local row 0..15
    int sr = start + h * 16 + lr;
    sr = (sr < count) ? sr : (count - 1);                // duplicate last row if padded
    const int grow = sorted[bucket * CAP + sr];
    const int co = ((lane & 15) * 16) ^ ((lr & 7) << 4); // swizzled 16B chunk
    aP[q] = (const char*)x + (size_t)grow * (L1D * 4) + co;
  }
  const char* bP = (const char*)cw + ((size_t)bucket * 96 * 64 + lane) * 16; // +kk*1024
  char* slab = (char*)sm.st.slab[wid];

  float4v acc = {0.f, 0.f, 0.f, 0.f};

#define STAGE(BUF_, T_)                                                        \
  {                                                                            \
    char* d_ = slab + (BUF_) * 6144;                                           \
    _Pragma("unroll")                                                          \
    for (int q = 0; q < 4; ++q)                                                \
      gload_lds16(aP[q] + (T_) * 256, d_ + q * 1024);                          \
    _Pragma("unroll")                                                          \
    for (int ks = 0; ks < 2; ++ks)                                             \
      gload_lds16(bP + (size_t)((T_) * 2 + ks) * 1024, d_ + 4096 + ks * 1024); \
  }

#define BODY(BUF_, DOSTAGE_, NT_)                                              \
  {                                                                            \
    const char* base_ = slab + (BUF_) * 6144;                                  \
    const int r_ = lane & 15, sw_ = (r_ & 7) << 4;                             \
    short8 afr[2], bfr[2];                                                     \
    _Pragma("unroll")                                                          \
    for (int ks = 0; ks < 2; ++ks) {                                           \
      const int G_ = ks * 128 + (lane >> 4) * 32;                              \
      const float4v lo = *(const float4v*)(base_ + r_ * 256 + (G_ ^ sw_));     \
      const float4v hi = *(const float4v*)(base_ + r_ * 256 + ((G_ + 16) ^ sw_)); \
      afr[ks] = short8{(short)f2bf(lo.x), (short)f2bf(lo.y), (short)f2bf(lo.z),\
                       (short)f2bf(lo.w), (short)f2bf(hi.x), (short)f2bf(hi.y),\
                       (short)f2bf(hi.z), (short)f2bf(hi.w)};                  \
      bfr[ks] = *(const short8*)(base_ + 4096 + ks * 1024 + lane * 16);        \
    }                                                                          \
    asm volatile("" ::: "memory");  /* keep the re-stage below the reads */    \
    if (DOSTAGE_) STAGE(BUF_, NT_)                                             \
    _Pragma("unroll")                                                          \
    for (int ks = 0; ks < 2; ++ks)                                             \
      acc = __builtin_amdgcn_mfma_f32_16x16x32_bf16(afr[ks], bfr[ks], acc, 0, 0, 0); \
  }

  // prologue: tiles t(0)=p, t(1)=p+2 in flight (12 loads)
  STAGE(0, p)
  STAGE(1, p + 2)

#pragma unroll 2
  for (int idx = 0; idx < 22; ++idx) {
    asm volatile("s_waitcnt vmcnt(6)" ::: "memory");   // tile t(idx) landed; t(idx+1) in flight
    BODY(idx & 1, 1, 2 * (idx + 2) + p)                // re-stage t(idx+2) into just-freed buf
  }
  asm volatile("s_waitcnt vmcnt(6)" ::: "memory");
  BODY(0, 0, 0)                                        // idx 22
  asm volatile("s_waitcnt vmcnt(0)" ::: "memory");
  BODY(1, 0, 0)                                        // idx 23
#undef STAGE
#undef BODY

  __syncthreads();   // staging LDS dead; epilogue view begins

  // ---- epilogue: bucket-sliced tables + k-parity partial sums ----
  if (tid < 32) {
    const int sr = start + tid;
    sm.ep.rows[tid]  = (sr < count) ? sorted[bucket * CAP + sr] : -1;
    sm.ep.outwb[tid] = goutw[bucket * 32 + tid];
    sm.ep.l2bb[tid]  = gl2b[bucket * 32 + tid];
  }
  if (tid < 16) sm.ep.biasb[tid] = cb[bucket * 16 + tid];
  for (int i = tid; i < 960; i += 256) sm.ep.l2wb[i] = gl2w[bucket * 960 + i];
#pragma unroll
  for (int rg = 0; rg < 4; ++rg)       // C/D: col=lane&15, row=(lane>>4)*4+rg
    sm.ep.ygp[p][h * 16 + (lane >> 4) * 4 + rg][lane & 15] = acc[rg];
  __syncthreads();

  // tail network: 8 threads per row, 4 l2-neurons each, shuffle-reduce (width 8)
  {
    const int r = tid >> 3, q = tid & 7;
    const int grow = sm.ep.rows[r];
    float act[30];
#pragma unroll
    for (int c = 0; c < 15; ++c) {
      const float v = sm.ep.ygp[0][r][c] + sm.ep.ygp[1][r][c] + sm.ep.biasb[c];
      act[c]      = fminf(v * v * (127.0f / 128.0f), 1.0f);
      act[15 + c] = fminf(fmaxf(v, 0.0f), 1.0f);
    }
    const float y15 = sm.ep.ygp[0][r][15] + sm.ep.ygp[1][r][15] + sm.ep.biasb[15];
    float o = 0.0f;
#pragma unroll
    for (int nn = 0; nn < 4; ++nn) {
      const int n = q * 4 + nn;
      float s = sm.ep.l2bb[n];
#pragma unroll
      for (int k = 0; k < 30; ++k) s += act[k] * sm.ep.l2wb[n * 30 + k];
      s = fminf(fmaxf(s, 0.0f), 1.0f);
      o += s * sm.ep.outwb[n];
    }
    o += __shfl_down(o, 4, 8);
    o += __shfl_down(o, 2, 8);
    o += __shfl_down(o, 1, 8);
    if (q == 0 && grow >= 0) out[grow] = o + y15 + goutb[bucket];
  }
}

extern "C" void kernel_launch(void* const* d_in, const int* in_sizes, int n_in,
                              void* d_out, int out_size, void* d_ws, size_t ws_size,
                              hipStream_t stream) {
  const float* x    = (const float*)d_in[0];
  const int*   lsi  = (const int*)d_in[1];
  const float* l1w  = (const float*)d_in[2];
  const float* l1b  = (const float*)d_in[3];
  const float* l1fw = (const float*)d_in[4];
  const float* l1fb = (const float*)d_in[5];
  const float* l2w  = (const float*)d_in[6];
  const float* l2b  = (const float*)d_in[7];
  const float* outw = (const float*)d_in[8];
  const float* outb = (const float*)d_in[9];
  float* out = (float*)d_out;

  unsigned short* cw = (unsigned short*)d_ws;                         // 786432 B (fragment order)
  float* cb   = (float*)((char*)d_ws + 786432);                       // 512 B
  int*   cur  = (int*)  ((char*)d_ws + 786944);                       // 32 B
  int*   sorted = (int*)((char*)d_ws + 786976);                       // 8*4096*4 = 131072 B

  prep_kernel<<<dim3(12, 128), 256, 0, stream>>>(l1w, l1b, l1fw, l1fb, cw, cb, cur);
  scatter_kernel<<<NB / 256, 256, 0, stream>>>(lsi, cur, sorted);
  fused_kernel<<<8 * (CAP / 32), 256, 0, stream>>>(x, cw, cb, l2w, l2b, outw, outb,
                                                   cur, sorted, out);
}

// Round 5
// 303.027 us; speedup vs baseline: 1.2050x; 1.2050x over previous
//
#include <hip/hip_runtime.h>
#include <stdint.h>

#define L1D 3072
#define NB 16384
#define CAP 4096            // per-bucket storage stride in sorted[]
#define CHUNKS 80           // chunk slots per bucket; count~2048 -> ~64 used (+12 sigma margin)

typedef float  float4v  __attribute__((ext_vector_type(4)));
typedef short  short8   __attribute__((ext_vector_type(8)));

__device__ __forceinline__ unsigned short f2bf(float f) {
  uint32_t u = __builtin_bit_cast(uint32_t, f);
  u += 0x7fffu + ((u >> 16) & 1u);   // RNE; inputs are finite
  return (unsigned short)(u >> 16);
}

__device__ __forceinline__ void gload_lds16(const void* g, void* l) {
  __builtin_amdgcn_global_load_lds((const __attribute__((address_space(1))) unsigned int*)g,
                                   (__attribute__((address_space(3))) unsigned int*)l, 16, 0, 0);
}

// Combined weights PRE-FRAGMENTED in MFMA B-fragment order:
//   frag(ntile, kk, lane) = 16B at ((ntile*96 + kk)*64 + lane)*8 shorts
//   lane l = sub*16 + r holds W[ntile*16 + r][kk*32 + sub*8 .. +8]
// Also zeroes the bucket cursors (workspace is re-poisoned every iteration).
__global__ void prep_kernel(const float* __restrict__ l1w, const float* __restrict__ l1b,
                            const float* __restrict__ l1fw, const float* __restrict__ l1fb,
                            unsigned short* __restrict__ cw, float* __restrict__ cb,
                            int* __restrict__ cur) {
  const int n = blockIdx.y;                       // 0..127  (= bucket*16 + j)
  const int k = blockIdx.x * 256 + threadIdx.x;   // 0..3071
  const unsigned short v = f2bf(l1w[n * L1D + k] + l1fw[(n & 15) * L1D + k]);
  const int kk  = k >> 5;
  const int sub = (k >> 3) & 3;
  const int e   = k & 7;
  const int lane = sub * 16 + (n & 15);
  cw[(((n >> 4) * 96 + kk) * 64 + lane) * 8 + e] = v;
  if (blockIdx.x == 0 && n == 0 && threadIdx.x < 128)
    cb[threadIdx.x] = l1b[threadIdx.x] + l1fb[threadIdx.x & 15];
  if (blockIdx.x == 0 && n == 0 && threadIdx.x < 8) cur[threadIdx.x] = 0;
}

// Two-phase bucket sort: LDS histogram (fast LDS atomics), ONE global atomic
// per bucket per block (512 total, vs 16384 same-line device atomics in R4),
// then direct placement. Order within bucket irrelevant.
__global__ void scatter_kernel(const int* __restrict__ lsi, int* __restrict__ cur,
                               int* __restrict__ sorted) {
  __shared__ int hist[8], base[8];
  const int tid = threadIdx.x;
  if (tid < 8) hist[tid] = 0;
  __syncthreads();
  const int i = blockIdx.x * 256 + tid;
  const int b = lsi[i];
  const int slot = atomicAdd(&hist[b], 1);        // LDS-scope atomic
  __syncthreads();
  if (tid < 8) base[tid] = atomicAdd(&cur[tid], hist[tid]);
  __syncthreads();
  sorted[b * CAP + base[b] + slot] = i;
}

struct __align__(16) EpS {
  float ygp[2][32][20];               // K-half partial sums, padded stride
  float l2wb[960];                    // bucket slice of l2_w  [n*30+k]
  float outwb[32];
  float l2bb[32];
  float biasb[16];
  int   rows[32];
};                                    // 9408 B

union __align__(16) SMem {
  struct { char slab[4][2][6144]; } st;   // [wave][buf][ A:0..4095 | B:4096..6143 ]  = 48 KiB
  EpS ep;
};

// Per-block: 32 rows of ONE bucket -> one 16-col B tile. Waves split
// (m-half h, K-half p: tiles [p*24,(p+1)*24) -- contiguous 6KB/row stream);
// each wave runs a PRIVATE LDS double buffer with its own counted-vmcnt
// cadence -- no barriers in the main loop. Grid = chunk*8+bucket so the
// ~512 useful blocks are a dense prefix (R4's mapping idled half the CUs).
__global__ __launch_bounds__(256, 3) void fused_kernel(
    const float* __restrict__ x, const unsigned short* __restrict__ cw,
    const float* __restrict__ cb,
    const float* __restrict__ gl2w, const float* __restrict__ gl2b,
    const float* __restrict__ goutw, const float* __restrict__ goutb,
    const int* __restrict__ cur, const int* __restrict__ sorted,
    float* __restrict__ out) {
  __shared__ SMem sm;
  const int tid  = threadIdx.x;
  const int lane = tid & 63;
  const int wid  = tid >> 6;
  const int bucket = blockIdx.x & 7;     // bucket fast-varying -> dense useful prefix
  const int chunk  = blockIdx.x >> 3;
  const int count  = cur[bucket];
  const int start  = chunk * 32;
  if (start >= count) return;            // uniform: whole block exits before any barrier

  const int h = wid >> 1;                // m-half: rows h*16 .. h*16+15
  const int p = wid & 1;                 // K-half: tiles p*24 .. p*24+23

  // Per-lane global A pointers for the 4 stage-instructions (4 rows each).
  // XOR swizzle applied on the SOURCE column chunk (linear LDS dest; read
  // applies the same XOR) -> conflict-free frag reads. K-half folded in.
  const char* aP[4];
#pragma unroll
  for (int q = 0; q < 4; ++q) {
    const int lr = q * 4 + (lane >> 4);                  // local row 0..15
    int sr = start + h * 16 + lr;
    sr = (sr < count) ? sr : (count - 1);                // duplicate last row if padded
    const int grow = sorted[bucket * CAP + sr];
    const int co = ((lane & 15) * 16) ^ ((lr & 7) << 4); // swizzled 16B chunk
    aP[q] = (const char*)x + (size_t)grow * (L1D * 4) + p * 6144 + co;
  }
  const char* bP = (const char*)cw + ((size_t)bucket * 96 * 64 + lane) * 16
                 + (size_t)p * 48 * 1024;                // wave's K-half of the B tile
  char* slab = (char*)sm.st.slab[wid];

  float4v acc = {0.f, 0.f, 0.f, 0.f};

#define STAGE(BUF_, IDX_)                                                       \
  {                                                                             \
    char* d_ = slab + (BUF_) * 6144;                                            \
    _Pragma("unroll")                                                           \
    for (int q = 0; q < 4; ++q)                                                 \
      gload_lds16(aP[q] + (IDX_) * 256, d_ + q * 1024);                         \
    _Pragma("unroll")                                                           \
    for (int ks = 0; ks < 2; ++ks)                                              \
      gload_lds16(bP + (size_t)((IDX_) * 2 + ks) * 1024, d_ + 4096 + ks * 1024);\
  }

#define BODY(BUF_, DOSTAGE_, NIDX_)                                             \
  {                                                                             \
    const char* base_ = slab + (BUF_) * 6144;                                   \
    const int r_ = lane & 15, sw_ = (r_ & 7) << 4;                              \
    short8 afr[2], bfr[2];                                                      \
    _Pragma("unroll")                                                           \
    for (int ks = 0; ks < 2; ++ks) {                                            \
      const int G_ = ks * 128 + (lane >> 4) * 32;                               \
      const float4v lo = *(const float4v*)(base_ + r_ * 256 + (G_ ^ sw_));      \
      const float4v hi = *(const float4v*)(base_ + r_ * 256 + ((G_ + 16) ^ sw_));\
      afr[ks] = short8{(short)f2bf(lo.x), (short)f2bf(lo.y), (short)f2bf(lo.z), \
                       (short)f2bf(lo.w), (short)f2bf(hi.x), (short)f2bf(hi.y), \
                       (short)f2bf(hi.z), (short)f2bf(hi.w)};                   \
      bfr[ks] = *(const short8*)(base_ + 4096 + ks * 1024 + lane * 16);         \
    }                                                                           \
    asm volatile("" ::: "memory");  /* keep the re-stage below the reads */     \
    if (DOSTAGE_) STAGE(BUF_, NIDX_)                                            \
    _Pragma("unroll")                                                           \
    for (int ks = 0; ks < 2; ++ks)                                              \
      acc = __builtin_amdgcn_mfma_f32_16x16x32_bf16(afr[ks], bfr[ks], acc, 0, 0, 0); \
  }

  // prologue: local tiles 0,1 in flight (12 loads)
  STAGE(0, 0)
  STAGE(1, 1)

#pragma unroll 2
  for (int idx = 0; idx < 22; ++idx) {
    asm volatile("s_waitcnt vmcnt(6)" ::: "memory");   // tile idx landed; idx+1 in flight
    BODY(idx & 1, 1, idx + 2)                          // re-stage idx+2 into just-freed buf
  }
  asm volatile("s_waitcnt vmcnt(6)" ::: "memory");
  BODY(0, 0, 0)                                        // idx 22
  asm volatile("s_waitcnt vmcnt(0)" ::: "memory");
  BODY(1, 0, 0)                                        // idx 23
#undef STAGE
#undef BODY

  __syncthreads();   // staging LDS dead; epilogue view begins

  // ---- epilogue: bucket-sliced tables + K-half partial sums ----
  if (tid < 32) {
    const int sr = start + tid;
    sm.ep.rows[tid]  = (sr < count) ? sorted[bucket * CAP + sr] : -1;
    sm.ep.outwb[tid] = goutw[bucket * 32 + tid];
    sm.ep.l2bb[tid]  = gl2b[bucket * 32 + tid];
  }
  if (tid < 16) sm.ep.biasb[tid] = cb[bucket * 16 + tid];
  for (int i = tid; i < 960; i += 256) sm.ep.l2wb[i] = gl2w[bucket * 960 + i];
#pragma unroll
  for (int rg = 0; rg < 4; ++rg)       // C/D: col=lane&15, row=(lane>>4)*4+rg
    sm.ep.ygp[p][h * 16 + (lane >> 4) * 4 + rg][lane & 15] = acc[rg];
  __syncthreads();

  // tail network: 8 threads per row, 4 l2-neurons each, shuffle-reduce (width 8)
  {
    const int r = tid >> 3, q = tid & 7;
    const int grow = sm.ep.rows[r];
    float act[30];
#pragma unroll
    for (int c = 0; c < 15; ++c) {
      const float v = sm.ep.ygp[0][r][c] + sm.ep.ygp[1][r][c] + sm.ep.biasb[c];
      act[c]      = fminf(v * v * (127.0f / 128.0f), 1.0f);
      act[15 + c] = fminf(fmaxf(v, 0.0f), 1.0f);
    }
    const float y15 = sm.ep.ygp[0][r][15] + sm.ep.ygp[1][r][15] + sm.ep.biasb[15];
    float o = 0.0f;
#pragma unroll
    for (int nn = 0; nn < 4; ++nn) {
      const int n = q * 4 + nn;
      float s = sm.ep.l2bb[n];
#pragma unroll
      for (int k = 0; k < 30; ++k) s += act[k] * sm.ep.l2wb[n * 30 + k];
      s = fminf(fmaxf(s, 0.0f), 1.0f);
      o += s * sm.ep.outwb[n];
    }
    o += __shfl_down(o, 4, 8);
    o += __shfl_down(o, 2, 8);
    o += __shfl_down(o, 1, 8);
    if (q == 0 && grow >= 0) out[grow] = o + y15 + goutb[bucket];
  }
}

extern "C" void kernel_launch(void* const* d_in, const int* in_sizes, int n_in,
                              void* d_out, int out_size, void* d_ws, size_t ws_size,
                              hipStream_t stream) {
  const float* x    = (const float*)d_in[0];
  const int*   lsi  = (const int*)d_in[1];
  const float* l1w  = (const float*)d_in[2];
  const float* l1b  = (const float*)d_in[3];
  const float* l1fw = (const float*)d_in[4];
  const float* l1fb = (const float*)d_in[5];
  const float* l2w  = (const float*)d_in[6];
  const float* l2b  = (const float*)d_in[7];
  const float* outw = (const float*)d_in[8];
  const float* outb = (const float*)d_in[9];
  float* out = (float*)d_out;

  unsigned short* cw = (unsigned short*)d_ws;                         // 786432 B (fragment order)
  float* cb   = (float*)((char*)d_ws + 786432);                       // 512 B
  int*   cur  = (int*)  ((char*)d_ws + 786944);                       // 32 B
  int*   sorted = (int*)((char*)d_ws + 786976);                       // 8*4096*4 = 131072 B

  prep_kernel<<<dim3(12, 128), 256, 0, stream>>>(l1w, l1b, l1fw, l1fb, cw, cb, cur);
  scatter_kernel<<<NB / 256, 256, 0, stream>>>(lsi, cur, sorted);
  fused_kernel<<<8 * CHUNKS, 256, 0, stream>>>(x, cw, cb, l2w, l2b, outw, outb,
                                               cur, sorted, out);
}

// Round 6
// 299.114 us; speedup vs baseline: 1.2207x; 1.0131x over previous
//
#include <hip/hip_runtime.h>
#include <stdint.h>

#define L1D 3072
#define NB 16384
#define CAP 4096            // per-bucket storage stride in sorted[]
#define ROWS 16             // rows per fused block
#define CHUNKS 152          // 16-row chunk slots per bucket (mean 128, +9 sigma margin)
#define TITER 12            // big K-steps of 256 floats (1 KB per row per step)

typedef float  float4v  __attribute__((ext_vector_type(4)));
typedef short  short8   __attribute__((ext_vector_type(8)));

__device__ __forceinline__ unsigned short f2bf(float f) {
  uint32_t u = __builtin_bit_cast(uint32_t, f);
  u += 0x7fffu + ((u >> 16) & 1u);   // RNE; inputs are finite
  return (unsigned short)(u >> 16);
}

__device__ __forceinline__ void gload_lds16(const void* g, void* l) {
  __builtin_amdgcn_global_load_lds((const __attribute__((address_space(1))) unsigned int*)g,
                                   (__attribute__((address_space(3))) unsigned int*)l, 16, 0, 0);
}

// Combined weights PRE-FRAGMENTED in MFMA B-fragment order:
//   frag(bucket, kk, lane) = 16B at ((bucket*96 + kk)*64 + lane)*8 shorts
//   lane l = sub*16 + r holds W[bucket*16 + r][kk*32 + sub*8 .. +8]
__global__ void prep_kernel(const float* __restrict__ l1w, const float* __restrict__ l1b,
                            const float* __restrict__ l1fw, const float* __restrict__ l1fb,
                            unsigned short* __restrict__ cw, float* __restrict__ cb,
                            int* __restrict__ cur) {
  const int n = blockIdx.y;                       // 0..127  (= bucket*16 + j)
  const int k = blockIdx.x * 256 + threadIdx.x;   // 0..3071
  const unsigned short v = f2bf(l1w[n * L1D + k] + l1fw[(n & 15) * L1D + k]);
  const int kk  = k >> 5;
  const int sub = (k >> 3) & 3;
  const int e   = k & 7;
  const int lane = sub * 16 + (n & 15);
  cw[(((n >> 4) * 96 + kk) * 64 + lane) * 8 + e] = v;
  if (blockIdx.x == 0 && n == 0 && threadIdx.x < 128)
    cb[threadIdx.x] = l1b[threadIdx.x] + l1fb[threadIdx.x & 15];
  if (blockIdx.x == 0 && n == 0 && threadIdx.x < 8) cur[threadIdx.x] = 0;
}

// Two-phase bucket sort: LDS histogram, one global atomic per bucket per
// block (512 total), then direct placement. Order within bucket irrelevant.
__global__ void scatter_kernel(const int* __restrict__ lsi, int* __restrict__ cur,
                               int* __restrict__ sorted) {
  __shared__ int hist[8], base[8];
  const int tid = threadIdx.x;
  if (tid < 8) hist[tid] = 0;
  __syncthreads();
  const int i = blockIdx.x * 256 + tid;
  const int b = lsi[i];
  const int slot = atomicAdd(&hist[b], 1);        // LDS-scope atomic
  __syncthreads();
  if (tid < 8) base[tid] = atomicAdd(&cur[tid], hist[tid]);
  __syncthreads();
  sorted[b * CAP + base[b] + slot] = i;
}

struct __align__(16) EpS {
  float ygp[4][ROWS][20];             // per-wave K-quarter partials, padded stride
  float l2wb[960];                    // bucket slice of l2_w  [n*30+k]
  float outwb[32];
  float l2bb[32];
  float biasb[16];
  int   rows[ROWS];
};                                    // 9344 B

union __align__(16) SMem {
  struct {
    float Af[2][ROWS][256];           // 32 KiB: [buf][row][1KB chunk], source-XOR-swizzled
    unsigned short Bf[2][8][512];     // 16 KiB: [buf][kstep][lane*8+e]
  } st;                               // 49152 B -> 3 blocks/CU
  EpS ep;
};

// 1KB-granule staging: each A stage-instruction reads 1KB CONTIGUOUS from one
// x row (64 lanes x 16B) -- 4x the DRAM granule of R0-R5 (256B/row), which is
// the structure-independent limiter suspected from R0..R5 all landing 89-105us.
// Lockstep 4-wave pipeline, counted vmcnt(6), 24 barriers total. Waves split
// the 8 k-steps of each big tile (2 each); partials merge in the epilogue.
__global__ __launch_bounds__(256, 3) void fused_kernel(
    const float* __restrict__ x, const unsigned short* __restrict__ cw,
    const float* __restrict__ cb,
    const float* __restrict__ gl2w, const float* __restrict__ gl2b,
    const float* __restrict__ goutw, const float* __restrict__ goutb,
    const int* __restrict__ cur, const int* __restrict__ sorted,
    float* __restrict__ out) {
  __shared__ SMem sm;
  const int tid  = threadIdx.x;
  const int lane = tid & 63;
  const int wid  = tid >> 6;
  const int bucket = blockIdx.x & 7;     // bucket fast-varying -> dense useful prefix
  const int chunk  = blockIdx.x >> 3;
  const int count  = cur[bucket];
  const int start  = chunk * ROWS;
  if (start >= count) return;            // block-uniform: exits before any barrier

  // A staging: wave stages rows wid*4+q (q=0..3), 1KB contiguous each.
  // Source chunk pre-swizzled (lane ^ (row&7)); LDS linear; read re-applies XOR.
  const char* aP[4];
#pragma unroll
  for (int q = 0; q < 4; ++q) {
    const int br = wid * 4 + q;                          // block row 0..15
    int sr = start + br;
    sr = (sr < count) ? sr : (count - 1);                // duplicate last row if padded
    const int grow = sorted[bucket * CAP + sr];
    aP[q] = (const char*)x + (size_t)grow * (L1D * 4) + (size_t)(lane ^ (br & 7)) * 16;
  }
  // B staging: wave stages k-steps {2wid, 2wid+1} of each big tile.
  const char* bP = (const char*)cw + ((size_t)bucket * 96 * 64 + lane) * 16;

  float4v acc = {0.f, 0.f, 0.f, 0.f};

#define STAGE(BUF_, T_)                                                          \
  {                                                                              \
    _Pragma("unroll")                                                            \
    for (int q = 0; q < 4; ++q)                                                  \
      gload_lds16(aP[q] + (size_t)(T_) * 1024, &sm.st.Af[BUF_][wid * 4 + q][0]); \
    _Pragma("unroll")                                                            \
    for (int j = 0; j < 2; ++j)                                                  \
      gload_lds16(bP + (size_t)((T_) * 8 + wid * 2 + j) * 1024,                  \
                  &sm.st.Bf[BUF_][wid * 2 + j][0]);                              \
  }

#define COMPUTE(BUF_)                                                            \
  {                                                                              \
    const int r_ = lane & 15, s_ = (r_ & 7);                                     \
    _Pragma("unroll")                                                            \
    for (int kq = 0; kq < 2; ++kq) {                                             \
      const int ks = wid * 2 + kq;                                               \
      const int c1 = (ks * 128 + (lane >> 4) * 32) >> 4;  /* 16B chunk idx */    \
      const float4v lo = *(const float4v*)((const char*)&sm.st.Af[BUF_][r_][0]   \
                                           + ((c1 ^ s_) << 4));                  \
      const float4v hi = *(const float4v*)((const char*)&sm.st.Af[BUF_][r_][0]   \
                                           + (((c1 + 1) ^ s_) << 4));            \
      const short8 afr = short8{(short)f2bf(lo.x), (short)f2bf(lo.y),            \
                                (short)f2bf(lo.z), (short)f2bf(lo.w),            \
                                (short)f2bf(hi.x), (short)f2bf(hi.y),            \
                                (short)f2bf(hi.z), (short)f2bf(hi.w)};           \
      const short8 bfr = *(const short8*)&sm.st.Bf[BUF_][ks][lane * 8];          \
      acc = __builtin_amdgcn_mfma_f32_16x16x32_bf16(afr, bfr, acc, 0, 0, 0);     \
    }                                                                            \
  }

  // prologue: big tiles 0,1 in flight (12 loads/wave); wait tile 0 only
  STAGE(0, 0)
  STAGE(1, 1)
  asm volatile("s_waitcnt vmcnt(6)" ::: "memory");
  __builtin_amdgcn_s_barrier();

#pragma unroll 1
  for (int t = 0; t < TITER; ++t) {
    COMPUTE(t & 1)
    asm volatile("" ::: "memory");
    __builtin_amdgcn_s_barrier();                 // all waves done reading buf
    if (t + 2 < TITER) {
      STAGE(t & 1, t + 2)
      asm volatile("s_waitcnt vmcnt(6)" ::: "memory");   // tile t+1 landed; t+2 in flight
    } else {
      asm volatile("s_waitcnt vmcnt(0)" ::: "memory");
    }
    __builtin_amdgcn_s_barrier();                 // everyone's tile t+1 landed
  }
#undef STAGE
#undef COMPUTE

  __syncthreads();   // staging LDS dead; epilogue view begins

  // ---- epilogue: bucket-sliced tables + per-wave k-partials ----
  if (tid < ROWS) {
    const int sr = start + tid;
    sm.ep.rows[tid] = (sr < count) ? sorted[bucket * CAP + sr] : -1;
  }
  if (tid < 32) {
    sm.ep.outwb[tid] = goutw[bucket * 32 + tid];
    sm.ep.l2bb[tid]  = gl2b[bucket * 32 + tid];
  }
  if (tid >= 32 && tid < 48) sm.ep.biasb[tid - 32] = cb[bucket * 16 + (tid - 32)];
  for (int i = tid; i < 960; i += 256) sm.ep.l2wb[i] = gl2w[bucket * 960 + i];
#pragma unroll
  for (int rg = 0; rg < 4; ++rg)       // C/D: col=lane&15, row=(lane>>4)*4+rg
    sm.ep.ygp[wid][(lane >> 4) * 4 + rg][lane & 15] = acc[rg];
  __syncthreads();

  // tail network: 8 threads per row, 4 l2-neurons each, shuffle-reduce (width 8)
  if (tid < ROWS * 8) {
    const int r = tid >> 3, q = tid & 7;
    const int grow = sm.ep.rows[r];
    float act[30];
#pragma unroll
    for (int c = 0; c < 15; ++c) {
      const float v = sm.ep.ygp[0][r][c] + sm.ep.ygp[1][r][c] +
                      sm.ep.ygp[2][r][c] + sm.ep.ygp[3][r][c] + sm.ep.biasb[c];
      act[c]      = fminf(v * v * (127.0f / 128.0f), 1.0f);
      act[15 + c] = fminf(fmaxf(v, 0.0f), 1.0f);
    }
    const float y15 = sm.ep.ygp[0][r][15] + sm.ep.ygp[1][r][15] +
                      sm.ep.ygp[2][r][15] + sm.ep.ygp[3][r][15] + sm.ep.biasb[15];
    float o = 0.0f;
#pragma unroll
    for (int nn = 0; nn < 4; ++nn) {
      const int n = q * 4 + nn;
      float s = sm.ep.l2bb[n];
#pragma unroll
      for (int k = 0; k < 30; ++k) s += act[k] * sm.ep.l2wb[n * 30 + k];
      s = fminf(fmaxf(s, 0.0f), 1.0f);
      o += s * sm.ep.outwb[n];
    }
    o += __shfl_down(o, 4, 8);
    o += __shfl_down(o, 2, 8);
    o += __shfl_down(o, 1, 8);
    if (q == 0 && grow >= 0) out[grow] = o + y15 + goutb[bucket];
  }
}

extern "C" void kernel_launch(void* const* d_in, const int* in_sizes, int n_in,
                              void* d_out, int out_size, void* d_ws, size_t ws_size,
                              hipStream_t stream) {
  const float* x    = (const float*)d_in[0];
  const int*   lsi  = (const int*)d_in[1];
  const float* l1w  = (const float*)d_in[2];
  const float* l1b  = (const float*)d_in[3];
  const float* l1fw = (const float*)d_in[4];
  const float* l1fb = (const float*)d_in[5];
  const float* l2w  = (const float*)d_in[6];
  const float* l2b  = (const float*)d_in[7];
  const float* outw = (const float*)d_in[8];
  const float* outb = (const float*)d_in[9];
  float* out = (float*)d_out;

  unsigned short* cw = (unsigned short*)d_ws;                         // 786432 B (fragment order)
  float* cb   = (float*)((char*)d_ws + 786432);                       // 512 B
  int*   cur  = (int*)  ((char*)d_ws + 786944);                       // 32 B
  int*   sorted = (int*)((char*)d_ws + 786976);                       // 8*4096*4 = 131072 B

  prep_kernel<<<dim3(12, 128), 256, 0, stream>>>(l1w, l1b, l1fw, l1fb, cw, cb, cur);
  scatter_kernel<<<NB / 256, 256, 0, stream>>>(lsi, cur, sorted);
  fused_kernel<<<8 * CHUNKS, 256, 0, stream>>>(x, cw, cb, l2w, l2b, outw, outb,
                                               cur, sorted, out);
}